// Round 1
// baseline (1369.547 us; speedup 1.0000x reference)
//
#include <hip/hip_runtime.h>

// Direct stride-2 valid conv: x(32,128,112,112) * w(256,128,3,3) -> out(32,256,55,55), fp32.
// Round 1: correctness baseline. Each thread: 1 output pixel x NOUT couts.
// Weight indices are block-uniform -> scalar loads (no LDS). All windows in-bounds.

#define BATCH 32
#define CIN   128
#define H     112
#define W     112
#define COUT  256
#define OH    55
#define OW    55
#define NPIX  (OH * OW)   // 3025
#define NOUT  8           // couts per thread

__global__ __launch_bounds__(256) void MyConv_4063039062211_kernel(
    const float* __restrict__ x, const float* __restrict__ w, float* __restrict__ out)
{
    const int pix = blockIdx.x * 256 + threadIdx.x;
    if (pix >= NPIX) return;

    const int b     = blockIdx.z;
    const int cout0 = blockIdx.y * NOUT;
    const int oh    = pix / OW;
    const int ow    = pix - oh * OW;
    const int ih0   = oh * 2;
    const int iw0   = ow * 2;

    float acc[NOUT];
#pragma unroll
    for (int i = 0; i < NOUT; ++i) acc[i] = 0.f;

    const float* xb = x + ((size_t)b * CIN) * (H * W) + (size_t)ih0 * W + iw0;
    const float* wb = w + (size_t)cout0 * (CIN * 9);

    for (int cin = 0; cin < CIN; ++cin) {
        const float* xp = xb + (size_t)cin * (H * W);
        float xv[9];
#pragma unroll
        for (int r = 0; r < 3; ++r) {
            xv[r * 3 + 0] = xp[r * W + 0];
            xv[r * 3 + 1] = xp[r * W + 1];
            xv[r * 3 + 2] = xp[r * W + 2];
        }
#pragma unroll
        for (int c = 0; c < NOUT; ++c) {
            const float* wp = wb + (size_t)c * (CIN * 9) + cin * 9;
#pragma unroll
            for (int k = 0; k < 9; ++k) acc[c] = fmaf(wp[k], xv[k], acc[c]);
        }
    }

    const size_t obase = ((size_t)b * COUT + cout0) * NPIX + pix;
#pragma unroll
    for (int c = 0; c < NOUT; ++c) out[obase + (size_t)c * NPIX] = acc[c];
}

extern "C" void kernel_launch(void* const* d_in, const int* in_sizes, int n_in,
                              void* d_out, int out_size, void* d_ws, size_t ws_size,
                              hipStream_t stream) {
    const float* x   = (const float*)d_in[0];
    const float* wgt = (const float*)d_in[1];
    float* out       = (float*)d_out;

    dim3 grid((NPIX + 255) / 256, COUT / NOUT, BATCH);
    MyConv_4063039062211_kernel<<<grid, dim3(256), 0, stream>>>(x, wgt, out);
}

// Round 2
// 422.644 us; speedup vs baseline: 3.2404x; 3.2404x over previous
//
#include <hip/hip_runtime.h>

// Stride-2 valid conv as implicit GEMM on MFMA.
// x(32,128,112,112) fp32 * w(256,128,3,3) fp32 -> out(32,256,55,55) fp32
// GEMM: M=cout=256, N=b*oh*ow=96800, K=tap*cin=1152 (bf16 inputs, fp32 acc).
// Prepass: x -> channels-last bf16 xs[b][h][w][c]; w -> wt[tap][cout][cin] bf16.

#define BATCH 32
#define CIN   128
#define H     112
#define W     112
#define COUT  256
#define OH    55
#define OW    55
#define NPIX  (OH*OW)          // 3025
#define NTOT  (BATCH*NPIX)     // 96800

typedef __bf16 bf16x8 __attribute__((ext_vector_type(8)));
typedef float  f32x4  __attribute__((ext_vector_type(4)));

__device__ __forceinline__ unsigned short f2bf(float f) {
    unsigned u = __float_as_uint(f);
    u += 0x7FFFu + ((u >> 16) & 1u);   // round-to-nearest-even
    return (unsigned short)(u >> 16);
}

__device__ __forceinline__ void gld_lds16(const void* g, void* l) {
    __builtin_amdgcn_global_load_lds((__attribute__((address_space(1))) void*)g,
                                     (__attribute__((address_space(3))) void*)l,
                                     16, 0, 0);
}

// ---------- prepass: w (COUT,CIN,3,3) fp32 -> wt[tap][cout][cin] bf16 ----------
__global__ __launch_bounds__(256) void relayout_w_k(const float* __restrict__ w,
                                                    unsigned short* __restrict__ wt) {
    int o = blockIdx.x * 256 + threadIdx.x;   // o = (tap*COUT + cout)*CIN + cin
    if (o >= 9 * COUT * CIN) return;
    int cin  = o & (CIN - 1);
    int r    = o >> 7;                         // tap*COUT + cout
    int cout = r & (COUT - 1);
    int tap  = r >> 8;
    wt[o] = f2bf(w[((size_t)cout * CIN + cin) * 9 + tap]);
}

// ---------- prepass: x NCHW fp32 -> xs[b][h][w][c] bf16 (channels-last) ----------
__global__ __launch_bounds__(256) void relayout_x_k(const float* __restrict__ x,
                                                    unsigned short* __restrict__ xs) {
    __shared__ __align__(16) unsigned short tile[W * 130 + 2];  // [w][c], pitch 130 (conflict-free)
    const int bh = blockIdx.x;                                  // b*H + h
    const int b  = bh / H;
    const int h  = bh - b * H;
    const float* xr = x + (size_t)b * CIN * (H * W) + (size_t)h * W;  // xr[c*H*W + w]
    const int t = threadIdx.x;
    // load: coalesced along w, write LDS transposed [w][c]
    for (int e = t; e < CIN * W; e += 256) {
        int c = e / W;
        int w = e - c * W;
        tile[w * 130 + c] = f2bf(xr[(size_t)c * (H * W) + w]);
    }
    __syncthreads();
    // store: xs[bh][w][c], coalesced dword writes along c
    unsigned int* dst = (unsigned int*)(xs + (size_t)bh * (W * CIN));
    const unsigned int* src = (const unsigned int*)tile;
    for (int e = t; e < (W * CIN) / 2; e += 256) {
        int w  = e >> 6;       // CIN/2 = 64 dwords per w-row
        int c2 = e & 63;
        dst[e] = src[w * 65 + c2];
    }
}

// ---------- main: 128x128 tile MFMA GEMM, K = 9 taps x 128 cin ----------
__global__ __launch_bounds__(256) void conv_mfma_k(const unsigned short* __restrict__ xs,
                                                   const unsigned short* __restrict__ wt,
                                                   float* __restrict__ out) {
    __shared__ __align__(16) unsigned short Alds[128 * 32];  // [cout][cin]
    __shared__ __align__(16) unsigned short Blds[128 * 32];  // [pix][cin]

    const int t    = threadIdx.x;
    const int wave = t >> 6;
    const int lane = t & 63;
    const int m0   = blockIdx.y * 128;
    const int n0   = blockIdx.x * 128;

    // staging map: thread t -> row t>>2 (and +64 on 2nd issue), 8-cin chunk (t&3)*8
    const int srow = t >> 2;
    const int scol = (t & 3) * 8;
    unsigned short* ldsA = Alds + wave * 512;   // wave-uniform LDS base (lane*16B added by HW)
    unsigned short* ldsB = Blds + wave * 512;

    // per-thread B pixel bases (element offsets into xs), OOB clamped (masked at store)
    int xb[2];
#pragma unroll
    for (int i = 0; i < 2; ++i) {
        int nn = n0 + srow + i * 64;
        if (nn >= NTOT) nn = NTOT - 1;
        int b  = nn / NPIX;
        int rp = nn - b * NPIX;
        int oh = rp / OW;
        int ow = rp - oh * OW;
        xb[i] = ((b * H + 2 * oh) * W + 2 * ow) * CIN;
    }

    const int lrow   = lane & 15;
    const int koff   = (lane >> 4) * 8;
    const int wave_m = (wave & 1) * 64;
    const int wave_n = (wave >> 1) * 64;

    f32x4 acc[4][4];
#pragma unroll
    for (int mi = 0; mi < 4; ++mi)
#pragma unroll
        for (int ni = 0; ni < 4; ++ni)
            acc[mi][ni] = (f32x4){0.f, 0.f, 0.f, 0.f};

    for (int tap = 0; tap < 9; ++tap) {
        const int r = tap / 3;
        const int s = tap - 3 * r;
        const int toff = (r * W + s) * CIN;
        const unsigned short* wtap = wt + tap * (COUT * CIN) + (m0 + srow) * CIN + scol;
        const unsigned short* xst  = xs + toff + scol;
#pragma unroll
        for (int kb = 0; kb < 4; ++kb) {
            const int cin0 = kb * 32;
            gld_lds16(wtap + cin0,            ldsA);
            gld_lds16(wtap + 64 * CIN + cin0, ldsA + 2048);
            gld_lds16(xst + xb[0] + cin0,     ldsB);
            gld_lds16(xst + xb[1] + cin0,     ldsB + 2048);
            __syncthreads();

            bf16x8 af[4], bfr[4];
#pragma unroll
            for (int mi = 0; mi < 4; ++mi)
                af[mi] = *(const bf16x8*)(Alds + (wave_m + mi * 16 + lrow) * 32 + koff);
#pragma unroll
            for (int ni = 0; ni < 4; ++ni)
                bfr[ni] = *(const bf16x8*)(Blds + (wave_n + ni * 16 + lrow) * 32 + koff);
#pragma unroll
            for (int mi = 0; mi < 4; ++mi)
#pragma unroll
                for (int ni = 0; ni < 4; ++ni)
                    acc[mi][ni] = __builtin_amdgcn_mfma_f32_16x16x32_bf16(af[mi], bfr[ni], acc[mi][ni], 0, 0, 0);
            __syncthreads();
        }
    }

    // epilogue: D[m][n], col n = lane&15, row m = (lane>>4)*4 + reg
    long obase[4];
    int  okn[4];
#pragma unroll
    for (int ni = 0; ni < 4; ++ni) {
        int nn = n0 + wave_n + ni * 16 + lrow;
        okn[ni] = (nn < NTOT);
        if (!okn[ni]) nn = 0;
        int b   = nn / NPIX;
        int pix = nn - b * NPIX;
        obase[ni] = (long)b * (COUT * NPIX) + pix;
    }
    const int mrow = (lane >> 4) * 4;
#pragma unroll
    for (int mi = 0; mi < 4; ++mi) {
#pragma unroll
        for (int rr = 0; rr < 4; ++rr) {
            int  m  = m0 + wave_m + mi * 16 + mrow + rr;
            long mo = (long)m * NPIX;
#pragma unroll
            for (int ni = 0; ni < 4; ++ni)
                if (okn[ni]) out[obase[ni] + mo] = acc[mi][ni][rr];
        }
    }
}

// ---------- fallback (ws too small): R1 direct kernel ----------
__global__ __launch_bounds__(256) void direct_k(const float* __restrict__ x,
                                                const float* __restrict__ w,
                                                float* __restrict__ out) {
    const int pix = blockIdx.x * 256 + threadIdx.x;
    if (pix >= NPIX) return;
    const int b = blockIdx.z, cout0 = blockIdx.y * 8;
    const int oh = pix / OW, ow = pix - oh * OW;
    float acc[8];
#pragma unroll
    for (int i = 0; i < 8; ++i) acc[i] = 0.f;
    const float* xbp = x + ((size_t)b * CIN) * (H * W) + (size_t)(oh * 2) * W + ow * 2;
    const float* wb  = w + (size_t)cout0 * (CIN * 9);
    for (int cin = 0; cin < CIN; ++cin) {
        const float* xp = xbp + (size_t)cin * (H * W);
        float xv[9];
#pragma unroll
        for (int r = 0; r < 3; ++r) {
            xv[r * 3 + 0] = xp[r * W + 0];
            xv[r * 3 + 1] = xp[r * W + 1];
            xv[r * 3 + 2] = xp[r * W + 2];
        }
#pragma unroll
        for (int c = 0; c < 8; ++c) {
            const float* wp = wb + (size_t)c * (CIN * 9) + cin * 9;
#pragma unroll
            for (int k = 0; k < 9; ++k) acc[c] = fmaf(wp[k], xv[k], acc[c]);
        }
    }
    const size_t ob = ((size_t)b * COUT + cout0) * NPIX + pix;
#pragma unroll
    for (int c = 0; c < 8; ++c) out[ob + (size_t)c * NPIX] = acc[c];
}

extern "C" void kernel_launch(void* const* d_in, const int* in_sizes, int n_in,
                              void* d_out, int out_size, void* d_ws, size_t ws_size,
                              hipStream_t stream) {
    const float* x = (const float*)d_in[0];
    const float* w = (const float*)d_in[1];
    float* out = (float*)d_out;

    const size_t xs_elems = (size_t)BATCH * H * W * CIN;   // 51,380,224
    const size_t wt_elems = (size_t)9 * COUT * CIN;        // 294,912
    const size_t need = (xs_elems + wt_elems) * 2;         // ~103.4 MB

    if (ws_size >= need) {
        unsigned short* xs = (unsigned short*)d_ws;
        unsigned short* wt = xs + xs_elems;
        relayout_w_k<<<(9 * COUT * CIN + 255) / 256, 256, 0, stream>>>(w, wt);
        relayout_x_k<<<BATCH * H, 256, 0, stream>>>(x, xs);
        dim3 grid((NTOT + 127) / 128, COUT / 128);
        conv_mfma_k<<<grid, dim3(256), 0, stream>>>(xs, wt, out);
    } else {
        dim3 grid((NPIX + 255) / 256, COUT / 8, BATCH);
        direct_k<<<grid, dim3(256), 0, stream>>>(x, w, out);
    }
}

// Round 3
// 410.151 us; speedup vs baseline: 3.3391x; 1.0305x over previous
//
#include <hip/hip_runtime.h>

// Stride-2 valid conv as implicit GEMM on MFMA (bf16 in, fp32 acc).
// GEMM: M=cout=256, N=b*oh*ow=96800, K=tap*cin=1152.
// R3: conv K-loop pipelined (dbuf LDS, loads(k+1) issued between barrier and mfma(k));
//     relayout_x vectorized (float4 loads, b128 LDS reads, dwordx4 stores).

#define BATCH 32
#define CIN   128
#define H     112
#define W     112
#define COUT  256
#define OH    55
#define OW    55
#define NPIX  (OH*OW)          // 3025
#define NTOT  (BATCH*NPIX)     // 96800

typedef __bf16 bf16x8 __attribute__((ext_vector_type(8)));
typedef float  f32x4  __attribute__((ext_vector_type(4)));

__device__ __forceinline__ unsigned short f2bf(float f) {
    unsigned u = __float_as_uint(f);
    u += 0x7FFFu + ((u >> 16) & 1u);   // RNE
    return (unsigned short)(u >> 16);
}

__device__ __forceinline__ void gld_lds16(const void* g, void* l) {
    __builtin_amdgcn_global_load_lds((__attribute__((address_space(1))) void*)g,
                                     (__attribute__((address_space(3))) void*)l,
                                     16, 0, 0);
}

// ---------- prepass: w (COUT,CIN,3,3) fp32 -> wt[tap][cout][cin] bf16 ----------
__global__ __launch_bounds__(256) void relayout_w_k(const float* __restrict__ w,
                                                    unsigned short* __restrict__ wt) {
    int o = blockIdx.x * 256 + threadIdx.x;
    if (o >= 9 * COUT * CIN) return;
    int cin  = o & (CIN - 1);
    int r    = o >> 7;
    int cout = r & (COUT - 1);
    int tap  = r >> 8;
    wt[o] = f2bf(w[((size_t)cout * CIN + cin) * 9 + tap]);
}

// ---------- prepass: x NCHW fp32 -> xs[b][h][w][c] bf16 ----------
#define XP 136   // LDS pitch in shorts: 272 B, 16-B aligned, bank-minimal phase-2 reads
__global__ __launch_bounds__(256) void relayout_x_k(const float* __restrict__ x,
                                                    unsigned short* __restrict__ xs) {
    __shared__ __align__(16) unsigned short tile[W * XP];
    const int bh = blockIdx.x;
    const int b  = bh / H;
    const int h  = bh - b * H;
    const float* xr = x + (size_t)b * CIN * (H * W) + (size_t)h * W;
    const int t = threadIdx.x;
    // phase 1: 3584 float4 loads (c-major rows, w-contiguous), transposed b16 writes
#pragma unroll
    for (int i = 0; i < 14; ++i) {
        int e  = t + i * 256;            // < 3584 = 128*28
        int c  = e / 28;
        int w4 = e - c * 28;
        float4 v = *(const float4*)(xr + (size_t)c * (H * W) + w4 * 4);
        int base = (w4 * 4) * XP + c;
        tile[base]          = f2bf(v.x);
        tile[base + XP]     = f2bf(v.y);
        tile[base + 2 * XP] = f2bf(v.z);
        tile[base + 3 * XP] = f2bf(v.w);
    }
    __syncthreads();
    // phase 2: b128 LDS reads, dwordx4 coalesced global stores
    uint4* dst = (uint4*)(xs + (size_t)bh * (W * CIN));
#pragma unroll
    for (int i = 0; i < 7; ++i) {
        int e  = t + i * 256;            // < 1792 = 112*16
        int w  = e >> 4;
        int c8 = e & 15;
        dst[e] = *(const uint4*)(tile + w * XP + c8 * 8);
    }
}

// ---------- main: 128x128 tile, BK=32, double-buffered pipelined K-loop ----------
__global__ __launch_bounds__(256) void conv_mfma_k(const unsigned short* __restrict__ xs,
                                                   const unsigned short* __restrict__ wt,
                                                   float* __restrict__ out) {
    __shared__ __align__(16) unsigned short Alds[2][128 * 32];
    __shared__ __align__(16) unsigned short Blds[2][128 * 32];

    const int t    = threadIdx.x;
    const int wave = t >> 6;
    const int lane = t & 63;
    const int m0   = blockIdx.y * 128;
    const int n0   = blockIdx.x * 128;

    const int srow = t >> 2;            // staging row
    const int scol = (t & 3) * 8;       // staging 8-cin chunk

    int xb[2];
#pragma unroll
    for (int i = 0; i < 2; ++i) {
        int nn = n0 + srow + i * 64;
        if (nn >= NTOT) nn = NTOT - 1;
        int b  = nn / NPIX;
        int rp = nn - b * NPIX;
        int oh = rp / OW;
        int ow = rp - oh * OW;
        xb[i] = ((b * H + 2 * oh) * W + 2 * ow) * CIN;
    }

    const int lrow   = lane & 15;
    const int koff   = (lane >> 4) * 8;
    const int wave_m = (wave & 1) * 64;
    const int wave_n = (wave >> 1) * 64;

    f32x4 acc[4][4];
#pragma unroll
    for (int mi = 0; mi < 4; ++mi)
#pragma unroll
        for (int ni = 0; ni < 4; ++ni)
            acc[mi][ni] = (f32x4){0.f, 0.f, 0.f, 0.f};

    // issue global->LDS loads for flat kstep ks into buffer buf
    auto issue = [&](int ks, int buf) {
        int tap  = ks >> 2;
        int cin0 = (ks & 3) * 32;
        int r    = (tap >= 6) ? 2 : (tap >= 3) ? 1 : 0;
        int s    = tap - 3 * r;
        int toff = (r * W + s) * CIN;
        const unsigned short* wtap = wt + tap * (COUT * CIN) + (m0 + srow) * CIN + scol + cin0;
        const unsigned short* xst  = xs + toff + scol + cin0;
        unsigned short* la = &Alds[buf][0] + wave * 512;
        unsigned short* lb = &Blds[buf][0] + wave * 512;
        gld_lds16(wtap,             la);
        gld_lds16(wtap + 64 * CIN,  la + 2048);
        gld_lds16(xst + xb[0],      lb);
        gld_lds16(xst + xb[1],      lb + 2048);
    };

    issue(0, 0);
#pragma unroll 2
    for (int ks = 0; ks < 36; ++ks) {
        const int buf = ks & 1;
        __syncthreads();                       // drains loads(ks) (in flight one full step)
        if (ks + 1 < 36) issue(ks + 1, buf ^ 1);  // overlap with mfma(ks) below

        bf16x8 af[4], bfr[4];
#pragma unroll
        for (int mi = 0; mi < 4; ++mi)
            af[mi] = *(const bf16x8*)(&Alds[buf][0] + (wave_m + mi * 16 + lrow) * 32 + koff);
#pragma unroll
        for (int ni = 0; ni < 4; ++ni)
            bfr[ni] = *(const bf16x8*)(&Blds[buf][0] + (wave_n + ni * 16 + lrow) * 32 + koff);
#pragma unroll
        for (int mi = 0; mi < 4; ++mi)
#pragma unroll
            for (int ni = 0; ni < 4; ++ni)
                acc[mi][ni] = __builtin_amdgcn_mfma_f32_16x16x32_bf16(af[mi], bfr[ni], acc[mi][ni], 0, 0, 0);
    }

    // epilogue: D[m][n], col n = lane&15, row m = (lane>>4)*4 + reg
    long obase[4];
    int  okn[4];
#pragma unroll
    for (int ni = 0; ni < 4; ++ni) {
        int nn = n0 + wave_n + ni * 16 + lrow;
        okn[ni] = (nn < NTOT);
        if (!okn[ni]) nn = 0;
        int b   = nn / NPIX;
        int pix = nn - b * NPIX;
        obase[ni] = (long)b * (COUT * NPIX) + pix;
    }
    const int mrow = (lane >> 4) * 4;
#pragma unroll
    for (int mi = 0; mi < 4; ++mi) {
#pragma unroll
        for (int rr = 0; rr < 4; ++rr) {
            int  m  = m0 + wave_m + mi * 16 + mrow + rr;
            long mo = (long)m * NPIX;
#pragma unroll
            for (int ni = 0; ni < 4; ++ni)
                if (okn[ni]) out[obase[ni] + mo] = acc[mi][ni][rr];
        }
    }
}

// ---------- fallback (ws too small): direct fp32 kernel ----------
__global__ __launch_bounds__(256) void direct_k(const float* __restrict__ x,
                                                const float* __restrict__ w,
                                                float* __restrict__ out) {
    const int pix = blockIdx.x * 256 + threadIdx.x;
    if (pix >= NPIX) return;
    const int b = blockIdx.z, cout0 = blockIdx.y * 8;
    const int oh = pix / OW, ow = pix - oh * OW;
    float acc[8];
#pragma unroll
    for (int i = 0; i < 8; ++i) acc[i] = 0.f;
    const float* xbp = x + ((size_t)b * CIN) * (H * W) + (size_t)(oh * 2) * W + ow * 2;
    const float* wb  = w + (size_t)cout0 * (CIN * 9);
    for (int cin = 0; cin < CIN; ++cin) {
        const float* xp = xbp + (size_t)cin * (H * W);
        float xv[9];
#pragma unroll
        for (int r = 0; r < 3; ++r) {
            xv[r * 3 + 0] = xp[r * W + 0];
            xv[r * 3 + 1] = xp[r * W + 1];
            xv[r * 3 + 2] = xp[r * W + 2];
        }
#pragma unroll
        for (int c = 0; c < 8; ++c) {
            const float* wp = wb + (size_t)c * (CIN * 9) + cin * 9;
#pragma unroll
            for (int k = 0; k < 9; ++k) acc[c] = fmaf(wp[k], xv[k], acc[c]);
        }
    }
    const size_t ob = ((size_t)b * COUT + cout0) * NPIX + pix;
#pragma unroll
    for (int c = 0; c < 8; ++c) out[ob + (size_t)c * NPIX] = acc[c];
}

extern "C" void kernel_launch(void* const* d_in, const int* in_sizes, int n_in,
                              void* d_out, int out_size, void* d_ws, size_t ws_size,
                              hipStream_t stream) {
    const float* x = (const float*)d_in[0];
    const float* w = (const float*)d_in[1];
    float* out = (float*)d_out;

    const size_t xs_elems = (size_t)BATCH * H * W * CIN;
    const size_t wt_elems = (size_t)9 * COUT * CIN;
    const size_t need = (xs_elems + wt_elems) * 2;

    if (ws_size >= need) {
        unsigned short* xs = (unsigned short*)d_ws;
        unsigned short* wt = xs + xs_elems;
        relayout_w_k<<<(9 * COUT * CIN + 255) / 256, 256, 0, stream>>>(w, wt);
        relayout_x_k<<<BATCH * H, 256, 0, stream>>>(x, xs);
        dim3 grid((NTOT + 127) / 128, COUT / 128);
        conv_mfma_k<<<grid, dim3(256), 0, stream>>>(xs, wt, out);
    } else {
        dim3 grid((NPIX + 255) / 256, COUT / 8, BATCH);
        direct_k<<<grid, dim3(256), 0, stream>>>(x, w, out);
    }
}